// Round 4
// baseline (96.298 us; speedup 1.0000x reference)
//
#include <hip/hip_runtime.h>

// n-step return: T=1024, B=4096, gamma=0.99, horizon=16, fp32 in/out.
// G[t,b] = sum_{h=0}^{15} g^h * rm[t+h,b]  (rm = rewards*masks, zero-padded past T)
//        + g^{min(t+16,T)-t} * values[min(t+15,T-1), b]
//
// R3 post-mortem: deep per-wave load bursts at 8 waves/CU plateau at ~3 TB/s.
// R4: max-TLP regime like the 6.4TB/s fill kernel: float2, CT=4, VGPR<=~80,
// ~28 waves/CU, 2048 blocks. rm halo (19 rows per 4 outputs, 4.75x) is served
// by L2: grid (8,256) puts t-adjacent chunks on the same XCD (delta id=8).
// HBM compulsory traffic stays ~64MB -> ~10us floor.

constexpr int   T_DIM  = 1024;
constexpr int   B_DIM  = 4096;
constexpr int   B2     = B_DIM / 2;   // 2048 float2 columns
constexpr int   H      = 16;          // horizon
constexpr int   CT     = 4;           // timesteps per thread
constexpr int   ROWS   = CT + H - 1;  // 19 staged rm rows
constexpr float GAMMA  = 0.99f;

constexpr float gpow_c(int n) {
    float g = 1.0f;
    for (int i = 0; i < n; ++i) g *= GAMMA;
    return g;
}
constexpr float G16 = gpow_c(16);

__global__ __launch_bounds__(256, 6)   // cap VGPR ~85 -> ~24-28 waves/CU
void NStepReturn_88691074662796_kernel(const float2* __restrict__ rewards,
                                       const float2* __restrict__ values,
                                       const float2* __restrict__ masks,
                                       float2* __restrict__ out)
{
    const int c  = blockIdx.x * 256 + threadIdx.x;        // float2 column (0..2047)
    const int t0 = blockIdx.y * CT;                       // chunk start

    // ---- stage bootstrap values (independent loads, in flight early) ----
    float2 v[CT];
    #pragma unroll
    for (int i = 0; i < CT; ++i) {
        const int vi = min(t0 + i + H - 1, T_DIM - 1);
        v[i] = values[vi * B2 + c];
    }

    // ---- stage rm = rewards*masks for 19 rows ----
    float2 rm[ROWS];
    #pragma unroll
    for (int i = 0; i < ROWS; ++i) {
        const int t = t0 + i;
        if (t < T_DIM) {
            const float2 r = rewards[t * B2 + c];
            const float2 m = masks[t * B2 + c];
            rm[i] = make_float2(r.x * m.x, r.y * m.y);
        } else {
            rm[i] = make_float2(0.f, 0.f);
        }
    }

    // ---- W(t0+3) = sum_{h=0}^{15} g^h rm[t0+3+h] (Horner) ----
    float2 W = make_float2(0.f, 0.f);
    #pragma unroll
    for (int h = H - 1; h >= 0; --h) {
        const float2 x = rm[CT - 1 + h];
        W.x = x.x + GAMMA * W.x;
        W.y = x.y + GAMMA * W.y;
    }

    {   // store t0+3
        const int t = t0 + CT - 1;
        float gb = G16;
        if (t + H > T_DIM) {                              // tail rows only
            gb = 1.0f;
            for (int k = 0; k < T_DIM - t; ++k) gb *= GAMMA;
        }
        out[t * B2 + c] = make_float2(W.x + gb * v[CT - 1].x,
                                      W.y + gb * v[CT - 1].y);
    }

    // ---- backward: W(t) = rm[t] + g*W(t+1) - g^16*rm[t+16] ----
    #pragma unroll
    for (int j = CT - 2; j >= 0; --j) {
        const int t = t0 + j;
        W.x = rm[j].x + GAMMA * W.x - G16 * rm[j + H].x;
        W.y = rm[j].y + GAMMA * W.y - G16 * rm[j + H].y;

        float gb = G16;
        if (t + H > T_DIM) {
            gb = 1.0f;
            for (int k = 0; k < T_DIM - t; ++k) gb *= GAMMA;
        }
        out[t * B2 + c] = make_float2(W.x + gb * v[j].x,
                                      W.y + gb * v[j].y);
    }
}

extern "C" void kernel_launch(void* const* d_in, const int* in_sizes, int n_in,
                              void* d_out, int out_size, void* d_ws, size_t ws_size,
                              hipStream_t stream) {
    const float2* rewards = (const float2*)d_in[0];
    const float2* values  = (const float2*)d_in[1];
    const float2* masks   = (const float2*)d_in[2];
    float2* out = (float2*)d_out;

    dim3 grid(B2 / 256, T_DIM / CT);   // (8, 256) = 2048 blocks
    dim3 block(256);
    NStepReturn_88691074662796_kernel<<<grid, block, 0, stream>>>(rewards, values, masks, out);
}

// Round 5
// 92.935 us; speedup vs baseline: 1.0362x; 1.0362x over previous
//
#include <hip/hip_runtime.h>

// n-step return: T=1024, B=4096, gamma=0.99, horizon=16, fp32 in/out.
// G[t,b] = sum_{h=0}^{15} g^h * rm[t+h,b]  (rm = rewards*masks, zero-padded)
//        + g^{min(t+16,T)-t} * values[min(t+15,T-1), b]
//
// R4 post-mortem: per-thread staging couples TLP to halo amplification
// (CT=4 -> 28 waves/CU but 4.75x rm re-read; CT=16 -> 1.9x halo but 16 waves).
// R5: LDS-tiled. Block = 64 cols x 64 t-rows; cooperatively stage 79 rows of
// rm into LDS once (1.23x amplification), then 8 waves x 8-row subchunks run
// the sliding-window recurrence from LDS (2-way bank alias = free). Grid 1024
// blocks x 512 thr = 32 waves/CU (launch_bounds(512,8) keeps VGPR<=64).
// Traffic ~71 MB -> ~11-14 us at achievable BW.

constexpr int   T_DIM    = 1024;
constexpr int   B_DIM    = 4096;
constexpr int   H        = 16;          // horizon
constexpr int   COLS     = 64;          // columns per block
constexpr int   ROWS_OUT = 64;          // output rows per block
constexpr int   ROWS_LDS = ROWS_OUT + H - 1;   // 79 staged rm rows
constexpr int   BLOCK    = 512;         // 8 waves; wave == one 8-row subchunk
constexpr float GAMMA    = 0.99f;

constexpr float gpow_c(int n) {
    float g = 1.0f;
    for (int i = 0; i < n; ++i) g *= GAMMA;
    return g;
}
constexpr float G16 = gpow_c(16);

__global__ __launch_bounds__(BLOCK, 8)
void NStepReturn_88691074662796_kernel(const float* __restrict__ rewards,
                                       const float* __restrict__ values,
                                       const float* __restrict__ masks,
                                       float* __restrict__ out)
{
    __shared__ float rm[ROWS_LDS * COLS];   // 79*64*4 = 20224 B

    const int c0  = blockIdx.x * COLS;
    const int t0  = blockIdx.y * ROWS_OUT;
    const int tid = threadIdx.x;

    // compute-phase identity: wave s owns rows tbase..tbase+7, lane = column
    const int c     = tid & (COLS - 1);
    const int s     = tid >> 6;             // subchunk 0..7
    const int tbase = t0 + s * 8;

    // ---- stage bootstrap values first: 8 independent loads, consumed last ----
    float v[8];
    #pragma unroll
    for (int j = 0; j < 8; ++j) {
        const int vi = min(tbase + j + H - 1, T_DIM - 1);
        v[j] = values[vi * B_DIM + c0 + c];
    }

    // ---- cooperative staging: 79 rows x 64 cols of rm = r*m into LDS ----
    // linear index j = row*64 + col; stride BLOCK => 256B coalesced per wave
    #pragma unroll
    for (int base = 0; base < ROWS_LDS * COLS; base += BLOCK) {
        const int j = base + tid;
        if (j < ROWS_LDS * COLS) {
            const int i  = j >> 6;          // row within tile
            const int cc = j & (COLS - 1);  // col within tile
            const int t  = t0 + i;
            float x = 0.0f;
            if (t < T_DIM) {
                x = rewards[t * B_DIM + c0 + cc] * masks[t * B_DIM + c0 + cc];
            }
            rm[j] = x;
        }
    }
    __syncthreads();

    // ---- sliding-window recurrence from LDS ----
    const float* col = &rm[(s * 8) * COLS + c];   // row stride COLS

    // init: W(tbase+7) = sum_{h=0}^{15} g^h rm[tbase+7+h]  (Horner, 16 taps)
    float W = 0.0f;
    #pragma unroll
    for (int h = H - 1; h >= 0; --h) {
        W = col[(7 + h) * COLS] + GAMMA * W;
    }

    {   // store row 7
        const int t = tbase + 7;
        float gb = G16;
        if (t + H > T_DIM) {                // only in grid's last t-chunk
            gb = 1.0f;
            for (int k = 0; k < T_DIM - t; ++k) gb *= GAMMA;
        }
        out[t * B_DIM + c0 + c] = W + gb * v[7];
    }

    // backward: W(t) = rm[t] + g*W(t+1) - g^16*rm[t+16]
    #pragma unroll
    for (int j = 6; j >= 0; --j) {
        W = col[j * COLS] + GAMMA * W - G16 * col[(j + H) * COLS];

        const int t = tbase + j;
        float gb = G16;
        if (t + H > T_DIM) {
            gb = 1.0f;
            for (int k = 0; k < T_DIM - t; ++k) gb *= GAMMA;
        }
        out[t * B_DIM + c0 + c] = W + gb * v[j];
    }
}

extern "C" void kernel_launch(void* const* d_in, const int* in_sizes, int n_in,
                              void* d_out, int out_size, void* d_ws, size_t ws_size,
                              hipStream_t stream) {
    const float* rewards = (const float*)d_in[0];
    const float* values  = (const float*)d_in[1];
    const float* masks   = (const float*)d_in[2];
    float* out = (float*)d_out;

    dim3 grid(B_DIM / COLS, T_DIM / ROWS_OUT);   // (64, 16) = 1024 blocks
    dim3 block(BLOCK);
    NStepReturn_88691074662796_kernel<<<grid, block, 0, stream>>>(rewards, values, masks, out);
}